// Round 7
// baseline (918.161 us; speedup 1.0000x reference)
//
#include <hip/hip_runtime.h>
#include <hip/hip_bf16.h>

typedef __attribute__((ext_vector_type(8))) short bf16x8;
typedef __attribute__((ext_vector_type(4))) float f32x4;

constexpr int BATCH = 32, SEQ = 3136, DIM = 768, NH = 12, HD = 64;
constexpr int M_TOT = BATCH * SEQ;   // 100352
constexpr int QKVC  = 3 * DIM;       // 2304
constexpr int GK    = 768;           // K for both GEMMs

__device__ __forceinline__ float bf2f(unsigned short u) {
  union { unsigned int i; float f; } x; x.i = ((unsigned int)u) << 16; return x.f;
}
__device__ __forceinline__ unsigned short f2bf(float f) {
  union { float f; unsigned int i; } x; x.f = f;
  unsigned int r = x.i + 0x7FFFu + ((x.i >> 16) & 1u);
  return (unsigned short)(r >> 16);
}
__device__ __forceinline__ unsigned int pack2(float lo, float hi) {
  return (unsigned int)f2bf(lo) | ((unsigned int)f2bf(hi) << 16);
}
__device__ __forceinline__ void gload_lds16(const unsigned short* g, unsigned short* l) {
  __builtin_amdgcn_global_load_lds(
      (const __attribute__((address_space(1))) void*)g,
      (__attribute__((address_space(3))) void*)l, 16, 0, 0);
}

#define BARX()  asm volatile("s_barrier" ::: "memory")
#define LGKM0() asm volatile("s_waitcnt lgkmcnt(0)" ::: "memory")
#define VM8()   asm volatile("s_waitcnt vmcnt(8)" ::: "memory")
#define VM6()   asm volatile("s_waitcnt vmcnt(6)" ::: "memory")
#define SB0()   __builtin_amdgcn_sched_barrier(0)

// ---------------- merged prep: fp32->bf16 conv + 2x weight transpose ----------------
__global__ void prep_kernel(const float* __restrict__ x, unsigned short* __restrict__ x_bf,
                            const float* __restrict__ w_qkv, unsigned short* __restrict__ wt_qkv,
                            const float* __restrict__ w_proj, unsigned short* __restrict__ wt_proj) {
  __shared__ float tile[32][33];
  int bid = blockIdx.x, t = threadIdx.x;
  if (bid < 2048) {
    long n = (long)M_TOT * DIM;
    long i = ((long)bid * 256 + t) * 8;
    long stride = (long)2048 * 256 * 8;
    for (; i < n; i += stride) {
      float4 a = *(const float4*)(x + i);
      float4 b = *(const float4*)(x + i + 4);
      uint4 o;
      o.x = pack2(a.x, a.y); o.y = pack2(a.z, a.w);
      o.z = pack2(b.x, b.y); o.w = pack2(b.z, b.w);
      *(uint4*)(x_bf + i) = o;
    }
  } else {
    const float* w; unsigned short* wt; int N, bx, by;
    if (bid < 2048 + 1728) {
      int r = bid - 2048; w = w_qkv; wt = wt_qkv; N = QKVC; bx = r % 72; by = r / 72;
    } else {
      int r = bid - 3776; w = w_proj; wt = wt_proj; N = DIM; bx = r % 24; by = r / 24;
    }
    int n0 = bx * 32, k0 = by * 32;
    int tx = t & 31, ty = t >> 5;
    #pragma unroll
    for (int i = 0; i < 32; i += 8)
      tile[ty + i][tx] = w[(size_t)(k0 + ty + i) * N + n0 + tx];
    __syncthreads();
    #pragma unroll
    for (int i = 0; i < 32; i += 8)
      wt[(size_t)(n0 + ty + i) * GK + k0 + tx] = f2bf(tile[tx][ty + i]);
  }
}

// ---------------- persistent 256x256x64 GEMM: R5 schedule + intra-phase interleave ----------------
__device__ __forceinline__ void stage_half(const unsigned short* __restrict__ G, long row0, int col0,
                                           unsigned short* ldsHalf, int t) {
  int r = t >> 2;
  int gslot = (t & 3) ^ ((t >> 3) & 3);
  char* dst = (char*)ldsHalf + ((t >> 6) << 10);  // wave-uniform base; HW adds lane*16
  gload_lds16(G + (row0 + r) * (long)GK + col0 + gslot * 8, (unsigned short*)dst);
  gload_lds16(G + (row0 + 128 + r) * (long)GK + col0 + gslot * 8, (unsigned short*)(dst + 8192));
}
__device__ __forceinline__ bf16x8 frag(const unsigned short* half, int r, int ko) {
  return *(const bf16x8*)((const char*)half + r * 64 + ((((ko >> 3) ^ ((r >> 1) & 3))) << 4));
}

// Swapped operands: D = mfma(B, A): lane fl = C-row-within-16, regs = 4 consecutive C-cols.
#define MM4S(QM,AV,B0,B1,B2,B3) do { \
  acc[QM][0]=__builtin_amdgcn_mfma_f32_16x16x32_bf16(B0,AV,acc[QM][0],0,0,0); \
  acc[QM][1]=__builtin_amdgcn_mfma_f32_16x16x32_bf16(B1,AV,acc[QM][1],0,0,0); \
  acc[QM][2]=__builtin_amdgcn_mfma_f32_16x16x32_bf16(B2,AV,acc[QM][2],0,0,0); \
  acc[QM][3]=__builtin_amdgcn_mfma_f32_16x16x32_bf16(B3,AV,acc[QM][3],0,0,0); \
} while (0)

// R5 ledger (re-verified with stage at phase start; vmcnt order per phase unchanged):
//   VM6@P1(J) confirms S1,S2(J-1) = ks1(J) -> read in P2/P3.
//   VM6@P3(J) confirms S3,S4(J-1) = ks0(J+1) -> read in P4.
// WAR: each region's last ds_read drains (LGKM0) >=1 barrier before overwriting stage.
// Intra-phase: MFMA cluster split 4x MM4S with next-phase frag reads pinned between
// groups via sched_barrier(0); reads have no intra-phase register/data dependency.
#define KTILE_I(BUF, MA2, NB2, C2, MA3, NB3, C3) { \
  const unsigned short* Ah0 = &lds[BUF][0][0][0]; \
  const unsigned short* Ah1 = &lds[BUF][0][1][0]; \
  const unsigned short* Bh1 = &lds[BUF][1][1][0]; \
  const unsigned short* Ah0n = &lds[(BUF) ^ 1][0][0][0]; \
  const unsigned short* Bh0n = &lds[(BUF) ^ 1][1][0][0]; \
  /* P1: MFMA a0-3 x b0-3 (ks0/mq0); reads a4-7 (ks0 mq1); stage S1; VM6 */ \
  stage_half(A, MA2, C2, &lds[(BUF) ^ 1][0][1][0], t); \
  LGKM0(); SB0(); \
  __builtin_amdgcn_s_setprio(1); \
  MM4S(0, a0, b0, b1, b2, b3); SB0(); \
  a4 = frag(Ah0, ra + 64, ko); a5 = frag(Ah0, ra + 80, ko); SB0(); \
  MM4S(1, a1, b0, b1, b2, b3); SB0(); \
  a6 = frag(Ah0, ra + 96, ko); a7 = frag(Ah0, ra + 112, ko); SB0(); \
  MM4S(2, a2, b0, b1, b2, b3); \
  MM4S(3, a3, b0, b1, b2, b3); \
  __builtin_amdgcn_s_setprio(0); SB0(); \
  VM6(); BARX(); \
  /* P2: MFMA a4-7 x b0-3 (ks0/mq1); reads a0-3 (ks1 mq0) + b4-7 (ks1); stage S2 */ \
  stage_half(Bt, NB2, C2, &lds[(BUF) ^ 1][1][1][0], t); \
  LGKM0(); SB0(); \
  __builtin_amdgcn_s_setprio(1); \
  MM4S(4, a4, b0, b1, b2, b3); SB0(); \
  a0 = frag(Ah1, ra,      ko); a1 = frag(Ah1, ra + 16, ko); \
  a2 = frag(Ah1, ra + 32, ko); a3 = frag(Ah1, ra + 48, ko); SB0(); \
  MM4S(5, a5, b0, b1, b2, b3); SB0(); \
  b4 = frag(Bh1, rb, ko); b5 = frag(Bh1, rb + 16, ko); SB0(); \
  MM4S(6, a6, b0, b1, b2, b3); SB0(); \
  b6 = frag(Bh1, rb + 32, ko); b7 = frag(Bh1, rb + 48, ko); SB0(); \
  MM4S(7, a7, b0, b1, b2, b3); \
  __builtin_amdgcn_s_setprio(0); SB0(); \
  BARX(); \
  /* P3: MFMA a0-3 x b4-7 (ks1/mq0); reads a4-7 (ks1 mq1); stage S3; VM6 */ \
  stage_half(A, MA3, C3, &lds[BUF][0][0][0], t); \
  LGKM0(); SB0(); \
  __builtin_amdgcn_s_setprio(1); \
  MM4S(0, a0, b4, b5, b6, b7); SB0(); \
  a4 = frag(Ah1, ra + 64, ko); a5 = frag(Ah1, ra + 80, ko); SB0(); \
  MM4S(1, a1, b4, b5, b6, b7); SB0(); \
  a6 = frag(Ah1, ra + 96, ko); a7 = frag(Ah1, ra + 112, ko); SB0(); \
  MM4S(2, a2, b4, b5, b6, b7); \
  MM4S(3, a3, b4, b5, b6, b7); \
  __builtin_amdgcn_s_setprio(0); SB0(); \
  VM6(); BARX(); \
  /* P4: MFMA a4-7 x b4-7 (ks1/mq1); reads a0-3 + b0-3 (next ks0); stage S4 */ \
  stage_half(Bt, NB3, C3, &lds[BUF][1][0][0], t); \
  LGKM0(); SB0(); \
  __builtin_amdgcn_s_setprio(1); \
  MM4S(4, a4, b4, b5, b6, b7); SB0(); \
  a0 = frag(Ah0n, ra,      ko); a1 = frag(Ah0n, ra + 16, ko); \
  a2 = frag(Ah0n, ra + 32, ko); a3 = frag(Ah0n, ra + 48, ko); SB0(); \
  MM4S(5, a5, b4, b5, b6, b7); SB0(); \
  b0 = frag(Bh0n, rb, ko); b1 = frag(Bh0n, rb + 16, ko); SB0(); \
  MM4S(6, a6, b4, b5, b6, b7); SB0(); \
  b2 = frag(Bh0n, rb + 32, ko); b3 = frag(Bh0n, rb + 48, ko); SB0(); \
  MM4S(7, a7, b4, b5, b6, b7); \
  __builtin_amdgcn_s_setprio(0); SB0(); \
  BARX(); \
}

template<int OUTMODE, int NT>
__global__ __launch_bounds__(512, 2) void gemm256p(const unsigned short* __restrict__ A,
                                                   const unsigned short* __restrict__ Bt,
                                                   void* __restrict__ Cp,
                                                   const float* __restrict__ bias,
                                                   int Nld, int TPX) {
  __shared__ unsigned short lds[2][2][2][8192];  // [buf][A/B][ks][256*32], 128 KiB
  int t = threadIdx.x, lane = t & 63, wid = t >> 6;
  int wm = wid >> 2, wn = wid & 3;
  int bid = (int)blockIdx.x;
  int xcd = bid & 7, slot = bid >> 3;
  int tau = xcd * TPX + slot;
  int tend = (xcd + 1) * TPX;
  int fl = lane & 15, ko = (lane >> 4) * 8;
  int ra = wm * 128 + fl, rb = wn * 64 + fl;
  f32x4 acc[8][4];
  bf16x8 a0, a1, a2, a3, a4, a5, a6, a7, b0, b1, b2, b3, b4, b5, b6, b7;
  // prologue: stage buf0(ks0,ks1)+buf1(ks0); VM8 confirms buf0-ks0; prime a0-3,b0-3
  {
    long m0 = (long)(tau / NT) * 256, n0 = (long)(tau % NT) * 256;
    stage_half(A,  m0, 0,  &lds[0][0][0][0], t);
    stage_half(Bt, n0, 0,  &lds[0][1][0][0], t);
    stage_half(A,  m0, 32, &lds[0][0][1][0], t);
    stage_half(Bt, n0, 32, &lds[0][1][1][0], t);
    stage_half(A,  m0, 64, &lds[1][0][0][0], t);
    stage_half(Bt, n0, 64, &lds[1][1][0][0], t);
    VM8(); BARX();
    a0 = frag(&lds[0][0][0][0], ra,      ko); a1 = frag(&lds[0][0][0][0], ra + 16, ko);
    a2 = frag(&lds[0][0][0][0], ra + 32, ko); a3 = frag(&lds[0][0][0][0], ra + 48, ko);
    b0 = frag(&lds[0][1][0][0], rb,      ko); b1 = frag(&lds[0][1][0][0], rb + 16, ko);
    b2 = frag(&lds[0][1][0][0], rb + 32, ko); b3 = frag(&lds[0][1][0][0], rb + 48, ko);
  }
  #pragma unroll 1
  for (; tau < tend; tau += 32) {
    long m0 = (long)(tau / NT) * 256, n0 = (long)(tau % NT) * 256;
    int tn = (tau + 32 < tend) ? tau + 32 : tau;
    long m0n = (long)(tn / NT) * 256, n0n = (long)(tn % NT) * 256;
    #pragma unroll
    for (int i = 0; i < 8; ++i)
      #pragma unroll
      for (int j2 = 0; j2 < 4; ++j2) acc[i][j2] = (f32x4){0.f, 0.f, 0.f, 0.f};
    #pragma unroll 1
    for (int j = 0; j < 10; j += 2) {
      KTILE_I(0, m0, n0, j * 64 + 96,  m0, n0, j * 64 + 128);
      KTILE_I(1, m0, n0, j * 64 + 160, m0, n0, j * 64 + 192);
    }
    KTILE_I(0, m0,  n0,  736, m0n, n0n, 0);   // J=10: ks1(11) + next ks0(K0)
    KTILE_I(1, m0n, n0n, 32,  m0n, n0n, 64);  // J=11: next ks1(K0) + next ks0(K1)
    // epilogue: lane fl = row-within-16, (lane>>4)*4 = 4 consecutive cols -> vector stores
    int q4 = (lane >> 4) * 4;
    #pragma unroll
    for (int mf = 0; mf < 8; ++mf) {
      long row = m0 + wm * 128 + mf * 16 + fl;
      #pragma unroll
      for (int nf = 0; nf < 4; ++nf) {
        int col = (int)n0 + wn * 64 + nf * 16 + q4;
        if (OUTMODE == 0) {
          unsigned short* C = (unsigned short*)Cp;
          bool doexp = (n0 < 2 * DIM);
          float v0 = acc[mf][nf][0], v1 = acc[mf][nf][1], v2 = acc[mf][nf][2], v3 = acc[mf][nf][3];
          if (doexp) { v0 = __expf(v0); v1 = __expf(v1); v2 = __expf(v2); v3 = __expf(v3); }
          uint2 o; o.x = pack2(v0, v1); o.y = pack2(v2, v3);
          *(uint2*)(C + (size_t)row * Nld + col) = o;
        } else {
          float* C = (float*)Cp;
          float4 bb = *(const float4*)(bias + col);
          float4 o = { acc[mf][nf][0] + bb.x, acc[mf][nf][1] + bb.y,
                       acc[mf][nf][2] + bb.z, acc[mf][nf][3] + bb.w };
          *(float4*)(C + (size_t)row * Nld + col) = o;
        }
      }
    }
  }
}

// ---------------- ctx partials: chunk ch of 7, rows [ch*448,(ch+1)*448) ----------------
__global__ void ctx_part(const unsigned short* __restrict__ qkv, float* __restrict__ part,
                         float* __restrict__ dpart) {
  int blk = blockIdx.x;              // 384*7
  int bh = blk / 7, ch = blk - bh * 7;
  int b = bh / NH, h = bh % NH;
  __shared__ unsigned short Et[64 * 40];
  __shared__ unsigned short Vt[64 * 40];
  __shared__ float denom[64];
  int t = threadIdx.x, lane = t & 63, w = t >> 6;
  if (t < 64) denom[t] = 0.0f;
  int nl = t >> 3, e0 = (t & 7) * 8;
  int ko = (lane >> 4) * 8, fl = lane & 15;
  size_t base = (size_t)b * SEQ * QKVC + (size_t)h * HD;
  float dp[8] = {};
  f32x4 acc[4] = {};
  int c0b = ch * 448;
  for (int c0 = c0b; c0 < c0b + 448; c0 += 32) {
    __syncthreads();
    size_t rb = base + (size_t)(c0 + nl) * QKVC;
    uint4 kvec = *(const uint4*)(qkv + rb + DIM + e0);
    uint4 vvec = *(const uint4*)(qkv + rb + 2 * DIM + e0);
    const unsigned short* kp = (const unsigned short*)&kvec;
    const unsigned short* vp = (const unsigned short*)&vvec;
    #pragma unroll
    for (int j = 0; j < 8; ++j) {
      dp[j] += bf2f(kp[j]);
      Et[(e0 + j) * 40 + nl] = kp[j];
      Vt[(e0 + j) * 40 + nl] = vp[j];
    }
    __syncthreads();
    bf16x8 af = *(const bf16x8*)(Et + (w * 16 + fl) * 40 + ko);
    #pragma unroll
    for (int nf = 0; nf < 4; ++nf) {
      bf16x8 bv = *(const bf16x8*)(Vt + (nf * 16 + fl) * 40 + ko);
      acc[nf] = __builtin_amdgcn_mfma_f32_16x16x32_bf16(af, bv, acc[nf], 0, 0, 0);
    }
  }
  #pragma unroll
  for (int j = 0; j < 8; ++j) atomicAdd(&denom[e0 + j], dp[j]);
  __syncthreads();
  int r0 = (lane >> 4) * 4;
  float* pp = part + (size_t)blk * 4096;
  #pragma unroll
  for (int nf = 0; nf < 4; ++nf)
    #pragma unroll
    for (int r = 0; r < 4; ++r) {
      int c = w * 16 + r0 + r;
      int d = nf * 16 + fl;
      pp[d * 64 + c] = acc[nf][r];
    }
  if (t < 64) dpart[blk * 64 + t] = denom[t];
}

// ---------------- ctx reduce over 7 chunks -> ctxT[bh][d*64+c] bf16 ----------------
__global__ void ctx_reduce(const float* __restrict__ part, const float* __restrict__ dpart,
                           unsigned short* __restrict__ ctxT) {
  int bh = blockIdx.x, t = threadIdx.x;
  const float* pp = part + (size_t)bh * 7 * 4096;
  const float* dd = dpart + (size_t)bh * 7 * 64;
  #pragma unroll
  for (int i = 0; i < 16; ++i) {
    int idx = i * 256 + t;
    float s = 0.f, ds = 0.f;
    #pragma unroll
    for (int c = 0; c < 7; ++c) {
      s += pp[c * 4096 + idx];
      ds += dd[c * 64 + (idx & 63)];
    }
    ctxT[(size_t)bh * 4096 + idx] = f2bf(s / ds);
  }
}

// ---------------- PV: out[n][d] = (sum_c eq[n][c] ctx[c][d]) / sum_c eq[n][c] ----------------
__global__ void pv_kernel(const unsigned short* __restrict__ qkv, const unsigned short* __restrict__ ctxT,
                          unsigned short* __restrict__ aout) {
  int bid = blockIdx.x;
  int bh = bid / 49, chunk = bid - bh * 49;
  int b = bh / NH, h = bh % NH;
  int n0 = chunk * 64;
  __shared__ unsigned short P[64 * 80];
  __shared__ unsigned short CT[64 * 80];
  __shared__ float srow[64];
  int t = threadIdx.x, lane = t & 63, w = t >> 6;
  int ko = (lane >> 4) * 8, fl = lane & 15;
  if (t < 64) srow[t] = 0.0f;
  {
    int d = t >> 2, cq = (t & 3) * 16;
    const uint4* src = (const uint4*)(ctxT + (size_t)bh * 4096 + d * 64 + cq);
    *(uint4*)(CT + d * 80 + cq) = src[0];
    *(uint4*)(CT + d * 80 + cq + 8) = src[1];
  }
  __syncthreads();
  {
    int nl = t >> 2, cq = (t & 3) * 16;
    size_t rb = (size_t)(b * SEQ + n0 + nl) * QKVC + h * HD + cq;
    uint4 q0 = *(const uint4*)(qkv + rb);
    uint4 q1 = *(const uint4*)(qkv + rb + 8);
    *(uint4*)(P + nl * 80 + cq) = q0;
    *(uint4*)(P + nl * 80 + cq + 8) = q1;
    const unsigned short* qp0 = (const unsigned short*)&q0;
    const unsigned short* qp1 = (const unsigned short*)&q1;
    float s = 0.0f;
    #pragma unroll
    for (int j = 0; j < 8; ++j) s += bf2f(qp0[j]) + bf2f(qp1[j]);
    atomicAdd(&srow[nl], s);
  }
  __syncthreads();
  f32x4 acc[4] = {};
  #pragma unroll
  for (int kk = 0; kk < 2; ++kk) {
    bf16x8 af = *(const bf16x8*)(P + (w * 16 + fl) * 80 + kk * 32 + ko);
    #pragma unroll
    for (int nf = 0; nf < 4; ++nf) {
      bf16x8 bv = *(const bf16x8*)(CT + (nf * 16 + fl) * 80 + kk * 32 + ko);
      acc[nf] = __builtin_amdgcn_mfma_f32_16x16x32_bf16(af, bv, acc[nf], 0, 0, 0);
    }
  }
  int r0 = (lane >> 4) * 4;
  #pragma unroll
  for (int nf = 0; nf < 4; ++nf)
    #pragma unroll
    for (int r = 0; r < 4; ++r) {
      int nlr = w * 16 + r0 + r;
      int d = nf * 16 + fl;
      float v = acc[nf][r] / srow[nlr];
      aout[(size_t)(b * SEQ + n0 + nlr) * DIM + h * HD + d] = f2bf(v);
    }
}

extern "C" void kernel_launch(void* const* d_in, const int* in_sizes, int n_in,
                              void* d_out, int out_size, void* d_ws, size_t ws_size,
                              hipStream_t stream) {
  const float* x      = (const float*)d_in[0];
  const float* w_qkv  = (const float*)d_in[1];
  const float* w_proj = (const float*)d_in[2];
  const float* b_proj = (const float*)d_in[3];
  char* ws = (char*)d_ws;
  unsigned short* x_bf    = (unsigned short*)(ws);
  unsigned short* wt_qkv  = (unsigned short*)(ws + 154140672);
  unsigned short* wt_proj = (unsigned short*)(ws + 157679616);
  unsigned short* qkv     = (unsigned short*)(ws + 158859264);
  unsigned short* ctxT    = (unsigned short*)(ws + 154140672);  // alias wt_qkv (dead after GEMM1)
  float* part  = (float*)(ws);                 // alias x_bf region (dead after GEMM1), 44.0 MB
  float* dpart = (float*)(ws + 44040192);      // 688 KB
  unsigned short* aout = (unsigned short*)(ws);  // alias x_bf/part (partials dead after reduce)

  prep_kernel<<<4352, 256, 0, stream>>>(x, x_bf, w_qkv, wt_qkv, w_proj, wt_proj);
  gemm256p<0, 9><<<256, 512, 0, stream>>>(x_bf, wt_qkv, qkv, nullptr, QKVC, 441);
  ctx_part<<<BATCH * NH * 7, 256, 0, stream>>>(qkv, part, dpart);
  ctx_reduce<<<BATCH * NH, 256, 0, stream>>>(part, dpart, ctxT);
  pv_kernel<<<BATCH * NH * (SEQ / 64), 256, 0, stream>>>(qkv, ctxT, aout);
  gemm256p<1, 3><<<256, 512, 0, stream>>>(aout, wt_proj, (float*)d_out, b_proj, DIM, 147);
}

// Round 8
// 858.181 us; speedup vs baseline: 1.0699x; 1.0699x over previous
//
#include <hip/hip_runtime.h>
#include <hip/hip_bf16.h>

typedef __attribute__((ext_vector_type(8))) short bf16x8;
typedef __attribute__((ext_vector_type(4))) float f32x4;

constexpr int BATCH = 32, SEQ = 3136, DIM = 768, NH = 12, HD = 64;
constexpr int M_TOT = BATCH * SEQ;   // 100352
constexpr int QKVC  = 3 * DIM;       // 2304
constexpr int GK    = 768;           // K for both GEMMs

__device__ __forceinline__ float bf2f(unsigned short u) {
  union { unsigned int i; float f; } x; x.i = ((unsigned int)u) << 16; return x.f;
}
__device__ __forceinline__ unsigned short f2bf(float f) {
  union { float f; unsigned int i; } x; x.f = f;
  unsigned int r = x.i + 0x7FFFu + ((x.i >> 16) & 1u);
  return (unsigned short)(r >> 16);
}
__device__ __forceinline__ unsigned int pack2(float lo, float hi) {
  return (unsigned int)f2bf(lo) | ((unsigned int)f2bf(hi) << 16);
}
__device__ __forceinline__ void gload_lds16(const unsigned short* g, unsigned short* l) {
  __builtin_amdgcn_global_load_lds(
      (const __attribute__((address_space(1))) void*)g,
      (__attribute__((address_space(3))) void*)l, 16, 0, 0);
}

#define BARX()  asm volatile("s_barrier" ::: "memory")
#define LGKM0() asm volatile("s_waitcnt lgkmcnt(0)" ::: "memory")
#define VM8()   asm volatile("s_waitcnt vmcnt(8)" ::: "memory")
#define VM6()   asm volatile("s_waitcnt vmcnt(6)" ::: "memory")
#define SB0()   __builtin_amdgcn_sched_barrier(0)

// ---------------- merged prep: fp32->bf16 conv + 2x weight transpose ----------------
__global__ void prep_kernel(const float* __restrict__ x, unsigned short* __restrict__ x_bf,
                            const float* __restrict__ w_qkv, unsigned short* __restrict__ wt_qkv,
                            const float* __restrict__ w_proj, unsigned short* __restrict__ wt_proj) {
  __shared__ float tile[32][33];
  int bid = blockIdx.x, t = threadIdx.x;
  if (bid < 2048) {
    long n = (long)M_TOT * DIM;
    long i = ((long)bid * 256 + t) * 8;
    long stride = (long)2048 * 256 * 8;
    for (; i < n; i += stride) {
      float4 a = *(const float4*)(x + i);
      float4 b = *(const float4*)(x + i + 4);
      uint4 o;
      o.x = pack2(a.x, a.y); o.y = pack2(a.z, a.w);
      o.z = pack2(b.x, b.y); o.w = pack2(b.z, b.w);
      *(uint4*)(x_bf + i) = o;
    }
  } else {
    const float* w; unsigned short* wt; int N, bx, by;
    if (bid < 2048 + 1728) {
      int r = bid - 2048; w = w_qkv; wt = wt_qkv; N = QKVC; bx = r % 72; by = r / 72;
    } else {
      int r = bid - 3776; w = w_proj; wt = wt_proj; N = DIM; bx = r % 24; by = r / 24;
    }
    int n0 = bx * 32, k0 = by * 32;
    int tx = t & 31, ty = t >> 5;
    #pragma unroll
    for (int i = 0; i < 32; i += 8)
      tile[ty + i][tx] = w[(size_t)(k0 + ty + i) * N + n0 + tx];
    __syncthreads();
    #pragma unroll
    for (int i = 0; i < 32; i += 8)
      wt[(size_t)(n0 + ty + i) * GK + k0 + tx] = f2bf(tile[tx][ty + i]);
  }
}

// ---------------- persistent 256x256x64 GEMM, R5 schedule + swapped-operand epilogue ----------------
__device__ __forceinline__ void stage_half(const unsigned short* __restrict__ G, long row0, int col0,
                                           unsigned short* ldsHalf, int t) {
  int r = t >> 2;
  int gslot = (t & 3) ^ ((t >> 3) & 3);
  char* dst = (char*)ldsHalf + ((t >> 6) << 10);  // wave-uniform base; HW adds lane*16
  gload_lds16(G + (row0 + r) * (long)GK + col0 + gslot * 8, (unsigned short*)dst);
  gload_lds16(G + (row0 + 128 + r) * (long)GK + col0 + gslot * 8, (unsigned short*)(dst + 8192));
}
__device__ __forceinline__ bf16x8 frag(const unsigned short* half, int r, int ko) {
  return *(const bf16x8*)((const char*)half + r * 64 + ((((ko >> 3) ^ ((r >> 1) & 3))) << 4));
}

// Swapped operands: D = mfma(B, A): lane fl = C-row-within-16, regs = 4 consecutive C-cols
// (HW-verified R6/R7). acc[m-frag][n-frag] indexing unchanged.
#define MM16G(Q,A0,A1,A2,A3,B0,B1,B2,B3) do { \
  acc[(Q)+0][0]=__builtin_amdgcn_mfma_f32_16x16x32_bf16(B0,A0,acc[(Q)+0][0],0,0,0); \
  acc[(Q)+0][1]=__builtin_amdgcn_mfma_f32_16x16x32_bf16(B1,A0,acc[(Q)+0][1],0,0,0); \
  acc[(Q)+0][2]=__builtin_amdgcn_mfma_f32_16x16x32_bf16(B2,A0,acc[(Q)+0][2],0,0,0); \
  acc[(Q)+0][3]=__builtin_amdgcn_mfma_f32_16x16x32_bf16(B3,A0,acc[(Q)+0][3],0,0,0); \
  acc[(Q)+1][0]=__builtin_amdgcn_mfma_f32_16x16x32_bf16(B0,A1,acc[(Q)+1][0],0,0,0); \
  acc[(Q)+1][1]=__builtin_amdgcn_mfma_f32_16x16x32_bf16(B1,A1,acc[(Q)+1][1],0,0,0); \
  acc[(Q)+1][2]=__builtin_amdgcn_mfma_f32_16x16x32_bf16(B2,A1,acc[(Q)+1][2],0,0,0); \
  acc[(Q)+1][3]=__builtin_amdgcn_mfma_f32_16x16x32_bf16(B3,A1,acc[(Q)+1][3],0,0,0); \
  acc[(Q)+2][0]=__builtin_amdgcn_mfma_f32_16x16x32_bf16(B0,A2,acc[(Q)+2][0],0,0,0); \
  acc[(Q)+2][1]=__builtin_amdgcn_mfma_f32_16x16x32_bf16(B1,A2,acc[(Q)+2][1],0,0,0); \
  acc[(Q)+2][2]=__builtin_amdgcn_mfma_f32_16x16x32_bf16(B2,A2,acc[(Q)+2][2],0,0,0); \
  acc[(Q)+2][3]=__builtin_amdgcn_mfma_f32_16x16x32_bf16(B3,A2,acc[(Q)+2][3],0,0,0); \
  acc[(Q)+3][0]=__builtin_amdgcn_mfma_f32_16x16x32_bf16(B0,A3,acc[(Q)+3][0],0,0,0); \
  acc[(Q)+3][1]=__builtin_amdgcn_mfma_f32_16x16x32_bf16(B1,A3,acc[(Q)+3][1],0,0,0); \
  acc[(Q)+3][2]=__builtin_amdgcn_mfma_f32_16x16x32_bf16(B2,A3,acc[(Q)+3][2],0,0,0); \
  acc[(Q)+3][3]=__builtin_amdgcn_mfma_f32_16x16x32_bf16(B3,A3,acc[(Q)+3][3],0,0,0); \
} while (0)

// R5 K-tile, reads-after-MFMA order (best measured: 355us, MfmaUtil 46%).
// VM6 ledger: at VM6(P1,J) the 6 newer loads are S3,S4(J-1)+S1(J) -> confirms
// S1,S2(J-1)=ks1(J), read at end-P2(J) (one barrier later, all-waves-safe).
// VM6(P3,J) confirms S3,S4(J-1)=ks0(J+1), read at end-P4(J). Holds for prologue
// and across tile seams. WAR: every region's last ds_read drains (LGKM0) >=2
// barriers before its overwriting stage issues.
#define KTILE_W(BUF, MA2, NB2, C2, MA3, NB3, C3) { \
  const unsigned short* Ah0 = &lds[BUF][0][0][0]; \
  const unsigned short* Bh1 = &lds[BUF][1][1][0]; \
  const unsigned short* Ah1 = &lds[BUF][0][1][0]; \
  const unsigned short* Ah0n = &lds[(BUF) ^ 1][0][0][0]; \
  const unsigned short* Bh0n = &lds[(BUF) ^ 1][1][0][0]; \
  /* P1: MFMA ks0/mq0 (a0-3 x b0-3); reads a4-7 <- ks0 mq1; stage S1; VM6 */ \
  LGKM0(); SB0(); \
  __builtin_amdgcn_s_setprio(1); MM16G(0, a0, a1, a2, a3, b0, b1, b2, b3); \
  __builtin_amdgcn_s_setprio(0); SB0(); \
  a4 = frag(Ah0, ra + 64, ko); a5 = frag(Ah0, ra + 80, ko); \
  a6 = frag(Ah0, ra + 96, ko); a7 = frag(Ah0, ra + 112, ko); \
  stage_half(A, MA2, C2, &lds[(BUF) ^ 1][0][1][0], t); \
  VM6(); BARX(); \
  /* P2: MFMA ks0/mq1 (a4-7 x b0-3); reads a0-3 <- ks1 mq0, b4-7 <- ks1; stage S2 */ \
  LGKM0(); SB0(); \
  __builtin_amdgcn_s_setprio(1); MM16G(4, a4, a5, a6, a7, b0, b1, b2, b3); \
  __builtin_amdgcn_s_setprio(0); SB0(); \
  a0 = frag(Ah1, ra,      ko); a1 = frag(Ah1, ra + 16, ko); \
  a2 = frag(Ah1, ra + 32, ko); a3 = frag(Ah1, ra + 48, ko); \
  b4 = frag(Bh1, rb,      ko); b5 = frag(Bh1, rb + 16, ko); \
  b6 = frag(Bh1, rb + 32, ko); b7 = frag(Bh1, rb + 48, ko); \
  stage_half(Bt, NB2, C2, &lds[(BUF) ^ 1][1][1][0], t); \
  BARX(); \
  /* P3: MFMA ks1/mq0 (a0-3 x b4-7); reads a4-7 <- ks1 mq1; stage S3; VM6 */ \
  LGKM0(); SB0(); \
  __builtin_amdgcn_s_setprio(1); MM16G(0, a0, a1, a2, a3, b4, b5, b6, b7); \
  __builtin_amdgcn_s_setprio(0); SB0(); \
  a4 = frag(Ah1, ra + 64, ko); a5 = frag(Ah1, ra + 80, ko); \
  a6 = frag(Ah1, ra + 96, ko); a7 = frag(Ah1, ra + 112, ko); \
  stage_half(A, MA3, C3, &lds[BUF][0][0][0], t); \
  VM6(); BARX(); \
  /* P4: MFMA ks1/mq1 (a4-7 x b4-7); reads a0-3,b0-3 <- next ks0; stage S4 */ \
  LGKM0(); SB0(); \
  __builtin_amdgcn_s_setprio(1); MM16G(4, a4, a5, a6, a7, b4, b5, b6, b7); \
  __builtin_amdgcn_s_setprio(0); SB0(); \
  a0 = frag(Ah0n, ra,      ko); a1 = frag(Ah0n, ra + 16, ko); \
  a2 = frag(Ah0n, ra + 32, ko); a3 = frag(Ah0n, ra + 48, ko); \
  b0 = frag(Bh0n, rb,      ko); b1 = frag(Bh0n, rb + 16, ko); \
  b2 = frag(Bh0n, rb + 32, ko); b3 = frag(Bh0n, rb + 48, ko); \
  stage_half(Bt, NB3, C3, &lds[BUF][1][0][0], t); \
  BARX(); \
}

template<int OUTMODE, int NT>
__global__ __launch_bounds__(512, 2) void gemm256p(const unsigned short* __restrict__ A,
                                                   const unsigned short* __restrict__ Bt,
                                                   void* __restrict__ Cp,
                                                   const float* __restrict__ bias,
                                                   int Nld, int TPX) {
  __shared__ unsigned short lds[2][2][2][8192];  // [buf][A/B][ks][256*32], 128 KiB
  int t = threadIdx.x, lane = t & 63, wid = t >> 6;
  int wm = wid >> 2, wn = wid & 3;
  int bid = (int)blockIdx.x;
  int xcd = bid & 7, slot = bid >> 3;
  int tau = xcd * TPX + slot;
  int tend = (xcd + 1) * TPX;
  int fl = lane & 15, ko = (lane >> 4) * 8;
  int ra = wm * 128 + fl, rb = wn * 64 + fl;
  f32x4 acc[8][4];
  bf16x8 a0, a1, a2, a3, a4, a5, a6, a7, b0, b1, b2, b3, b4, b5, b6, b7;
  // prologue: stage buf0(ks0,ks1)+buf1(ks0); VM8 confirms buf0-ks0; prime a0-3,b0-3
  {
    long m0 = (long)(tau / NT) * 256, n0 = (long)(tau % NT) * 256;
    stage_half(A,  m0, 0,  &lds[0][0][0][0], t);
    stage_half(Bt, n0, 0,  &lds[0][1][0][0], t);
    stage_half(A,  m0, 32, &lds[0][0][1][0], t);
    stage_half(Bt, n0, 32, &lds[0][1][1][0], t);
    stage_half(A,  m0, 64, &lds[1][0][0][0], t);
    stage_half(Bt, n0, 64, &lds[1][1][0][0], t);
    VM8(); BARX();
    a0 = frag(&lds[0][0][0][0], ra,      ko); a1 = frag(&lds[0][0][0][0], ra + 16, ko);
    a2 = frag(&lds[0][0][0][0], ra + 32, ko); a3 = frag(&lds[0][0][0][0], ra + 48, ko);
    b0 = frag(&lds[0][1][0][0], rb,      ko); b1 = frag(&lds[0][1][0][0], rb + 16, ko);
    b2 = frag(&lds[0][1][0][0], rb + 32, ko); b3 = frag(&lds[0][1][0][0], rb + 48, ko);
  }
  #pragma unroll 1
  for (; tau < tend; tau += 32) {
    long m0 = (long)(tau / NT) * 256, n0 = (long)(tau % NT) * 256;
    int tn = (tau + 32 < tend) ? tau + 32 : tau;
    long m0n = (long)(tn / NT) * 256, n0n = (long)(tn % NT) * 256;
    #pragma unroll
    for (int i = 0; i < 8; ++i)
      #pragma unroll
      for (int j2 = 0; j2 < 4; ++j2) acc[i][j2] = (f32x4){0.f, 0.f, 0.f, 0.f};
    #pragma unroll 1
    for (int j = 0; j < 10; j += 2) {
      KTILE_W(0, m0, n0, j * 64 + 96,  m0, n0, j * 64 + 128);
      KTILE_W(1, m0, n0, j * 64 + 160, m0, n0, j * 64 + 192);
    }
    KTILE_W(0, m0,  n0,  736, m0n, n0n, 0);   // J=10: ks1(11) + next ks0(K0)
    KTILE_W(1, m0n, n0n, 32,  m0n, n0n, 64);  // J=11: next ks1(K0) + buf1 ks0(K1)
    // epilogue: lane fl = row-within-16, (lane>>4)*4 = 4 consecutive cols -> vector stores
    int q4 = (lane >> 4) * 4;
    #pragma unroll
    for (int mf = 0; mf < 8; ++mf) {
      long row = m0 + wm * 128 + mf * 16 + fl;
      #pragma unroll
      for (int nf = 0; nf < 4; ++nf) {
        int col = (int)n0 + wn * 64 + nf * 16 + q4;
        if (OUTMODE == 0) {
          unsigned short* C = (unsigned short*)Cp;
          bool doexp = (n0 < 2 * DIM);
          float v0 = acc[mf][nf][0], v1 = acc[mf][nf][1], v2 = acc[mf][nf][2], v3 = acc[mf][nf][3];
          if (doexp) { v0 = __expf(v0); v1 = __expf(v1); v2 = __expf(v2); v3 = __expf(v3); }
          uint2 o; o.x = pack2(v0, v1); o.y = pack2(v2, v3);
          *(uint2*)(C + (size_t)row * Nld + col) = o;
        } else {
          float* C = (float*)Cp;
          float4 bb = *(const float4*)(bias + col);
          float4 o = { acc[mf][nf][0] + bb.x, acc[mf][nf][1] + bb.y,
                       acc[mf][nf][2] + bb.z, acc[mf][nf][3] + bb.w };
          *(float4*)(C + (size_t)row * Nld + col) = o;
        }
      }
    }
  }
}

// ---------------- ctx partials: chunk ch of 7, rows [ch*448,(ch+1)*448) ----------------
__global__ void ctx_part(const unsigned short* __restrict__ qkv, float* __restrict__ part,
                         float* __restrict__ dpart) {
  int blk = blockIdx.x;              // 384*7
  int bh = blk / 7, ch = blk - bh * 7;
  int b = bh / NH, h = bh % NH;
  __shared__ unsigned short Et[64 * 40];
  __shared__ unsigned short Vt[64 * 40];
  __shared__ float denom[64];
  int t = threadIdx.x, lane = t & 63, w = t >> 6;
  if (t < 64) denom[t] = 0.0f;
  int nl = t >> 3, e0 = (t & 7) * 8;
  int ko = (lane >> 4) * 8, fl = lane & 15;
  size_t base = (size_t)b * SEQ * QKVC + (size_t)h * HD;
  float dp[8] = {};
  f32x4 acc[4] = {};
  int c0b = ch * 448;
  for (int c0 = c0b; c0 < c0b + 448; c0 += 32) {
    __syncthreads();
    size_t rb = base + (size_t)(c0 + nl) * QKVC;
    uint4 kvec = *(const uint4*)(qkv + rb + DIM + e0);
    uint4 vvec = *(const uint4*)(qkv + rb + 2 * DIM + e0);
    const unsigned short* kp = (const unsigned short*)&kvec;
    const unsigned short* vp = (const unsigned short*)&vvec;
    #pragma unroll
    for (int j = 0; j < 8; ++j) {
      dp[j] += bf2f(kp[j]);
      Et[(e0 + j) * 40 + nl] = kp[j];
      Vt[(e0 + j) * 40 + nl] = vp[j];
    }
    __syncthreads();
    bf16x8 af = *(const bf16x8*)(Et + (w * 16 + fl) * 40 + ko);
    #pragma unroll
    for (int nf = 0; nf < 4; ++nf) {
      bf16x8 bv = *(const bf16x8*)(Vt + (nf * 16 + fl) * 40 + ko);
      acc[nf] = __builtin_amdgcn_mfma_f32_16x16x32_bf16(af, bv, acc[nf], 0, 0, 0);
    }
  }
  #pragma unroll
  for (int j = 0; j < 8; ++j) atomicAdd(&denom[e0 + j], dp[j]);
  __syncthreads();
  int r0 = (lane >> 4) * 4;
  float* pp = part + (size_t)blk * 4096;
  #pragma unroll
  for (int nf = 0; nf < 4; ++nf)
    #pragma unroll
    for (int r = 0; r < 4; ++r) {
      int c = w * 16 + r0 + r;
      int d = nf * 16 + fl;
      pp[d * 64 + c] = acc[nf][r];
    }
  if (t < 64) dpart[blk * 64 + t] = denom[t];
}

// ---------------- ctx reduce over 7 chunks -> ctxT[bh][d*64+c] bf16 ----------------
__global__ void ctx_reduce(const float* __restrict__ part, const float* __restrict__ dpart,
                           unsigned short* __restrict__ ctxT) {
  int bh = blockIdx.x, t = threadIdx.x;
  const float* pp = part + (size_t)bh * 7 * 4096;
  const float* dd = dpart + (size_t)bh * 7 * 64;
  #pragma unroll
  for (int i = 0; i < 16; ++i) {
    int idx = i * 256 + t;
    float s = 0.f, ds = 0.f;
    #pragma unroll
    for (int c = 0; c < 7; ++c) {
      s += pp[c * 4096 + idx];
      ds += dd[c * 64 + (idx & 63)];
    }
    ctxT[(size_t)bh * 4096 + idx] = f2bf(s / ds);
  }
}

// ---------------- PV: out[n][d] = (sum_c eq[n][c] ctx[c][d]) / sum_c eq[n][c] ----------------
__global__ void pv_kernel(const unsigned short* __restrict__ qkv, const unsigned short* __restrict__ ctxT,
                          unsigned short* __restrict__ aout) {
  int bid = blockIdx.x;
  int bh = bid / 49, chunk = bid - bh * 49;
  int b = bh / NH, h = bh % NH;
  int n0 = chunk * 64;
  __shared__ unsigned short P[64 * 80];
  __shared__ unsigned short CT[64 * 80];
  __shared__ float srow[64];
  int t = threadIdx.x, lane = t & 63, w = t >> 6;
  int ko = (lane >> 4) * 8, fl = lane & 15;
  if (t < 64) srow[t] = 0.0f;
  {
    int d = t >> 2, cq = (t & 3) * 16;
    const uint4* src = (const uint4*)(ctxT + (size_t)bh * 4096 + d * 64 + cq);
    *(uint4*)(CT + d * 80 + cq) = src[0];
    *(uint4*)(CT + d * 80 + cq + 8) = src[1];
  }
  __syncthreads();
  {
    int nl = t >> 2, cq = (t & 3) * 16;
    size_t rb = (size_t)(b * SEQ + n0 + nl) * QKVC + h * HD + cq;
    uint4 q0 = *(const uint4*)(qkv + rb);
    uint4 q1 = *(const uint4*)(qkv + rb + 8);
    *(uint4*)(P + nl * 80 + cq) = q0;
    *(uint4*)(P + nl * 80 + cq + 8) = q1;
    const unsigned short* qp0 = (const unsigned short*)&q0;
    const unsigned short* qp1 = (const unsigned short*)&q1;
    float s = 0.0f;
    #pragma unroll
    for (int j = 0; j < 8; ++j) s += bf2f(qp0[j]) + bf2f(qp1[j]);
    atomicAdd(&srow[nl], s);
  }
  __syncthreads();
  f32x4 acc[4] = {};
  #pragma unroll
  for (int kk = 0; kk < 2; ++kk) {
    bf16x8 af = *(const bf16x8*)(P + (w * 16 + fl) * 80 + kk * 32 + ko);
    #pragma unroll
    for (int nf = 0; nf < 4; ++nf) {
      bf16x8 bv = *(const bf16x8*)(CT + (nf * 16 + fl) * 80 + kk * 32 + ko);
      acc[nf] = __builtin_amdgcn_mfma_f32_16x16x32_bf16(af, bv, acc[nf], 0, 0, 0);
    }
  }
  int r0 = (lane >> 4) * 4;
  #pragma unroll
  for (int nf = 0; nf < 4; ++nf)
    #pragma unroll
    for (int r = 0; r < 4; ++r) {
      int nlr = w * 16 + r0 + r;
      int d = nf * 16 + fl;
      float v = acc[nf][r] / srow[nlr];
      aout[(size_t)(b * SEQ + n0 + nlr) * DIM + h * HD + d] = f2bf(v);
    }
}

extern "C" void kernel_launch(void* const* d_in, const int* in_sizes, int n_in,
                              void* d_out, int out_size, void* d_ws, size_t ws_size,
                              hipStream_t stream) {
  const float* x      = (const float*)d_in[0];
  const float* w_qkv  = (const float*)d_in[1];
  const float* w_proj = (const float*)d_in[2];
  const float* b_proj = (const float*)d_in[3];
  char* ws = (char*)d_ws;
  unsigned short* x_bf    = (unsigned short*)(ws);
  unsigned short* wt_qkv  = (unsigned short*)(ws + 154140672);
  unsigned short* wt_proj = (unsigned short*)(ws + 157679616);
  unsigned short* qkv     = (unsigned short*)(ws + 158859264);
  unsigned short* ctxT    = (unsigned short*)(ws + 154140672);  // alias wt_qkv (dead after GEMM1)
  float* part  = (float*)(ws);                 // alias x_bf region (dead after GEMM1), 44.0 MB
  float* dpart = (float*)(ws + 44040192);      // 688 KB
  unsigned short* aout = (unsigned short*)(ws);  // alias x_bf/part (partials dead after reduce)

  prep_kernel<<<4352, 256, 0, stream>>>(x, x_bf, w_qkv, wt_qkv, w_proj, wt_proj);
  gemm256p<0, 9><<<256, 512, 0, stream>>>(x_bf, wt_qkv, qkv, nullptr, QKVC, 441);
  ctx_part<<<BATCH * NH * 7, 256, 0, stream>>>(qkv, part, dpart);
  ctx_reduce<<<BATCH * NH, 256, 0, stream>>>(part, dpart, ctxT);
  pv_kernel<<<BATCH * NH * (SEQ / 64), 256, 0, stream>>>(qkv, ctxT, aout);
  gemm256p<1, 3><<<256, 512, 0, stream>>>(aout, wt_proj, (float*)d_out, b_proj, DIM, 147);
}

// Round 9
// 835.715 us; speedup vs baseline: 1.0987x; 1.0269x over previous
//
#include <hip/hip_runtime.h>
#include <hip/hip_bf16.h>

typedef __attribute__((ext_vector_type(8))) short bf16x8;
typedef __attribute__((ext_vector_type(16))) float f32x16;

constexpr int BATCH = 32, SEQ = 3136, DIM = 768, NH = 12, HD = 64;
constexpr int M_TOT = BATCH * SEQ;   // 100352
constexpr int QKVC  = 3 * DIM;       // 2304
constexpr int GK    = 768;           // K for both GEMMs

typedef __attribute__((ext_vector_type(4))) float f32x4;

__device__ __forceinline__ float bf2f(unsigned short u) {
  union { unsigned int i; float f; } x; x.i = ((unsigned int)u) << 16; return x.f;
}
__device__ __forceinline__ unsigned short f2bf(float f) {
  union { float f; unsigned int i; } x; x.f = f;
  unsigned int r = x.i + 0x7FFFu + ((x.i >> 16) & 1u);
  return (unsigned short)(r >> 16);
}
__device__ __forceinline__ unsigned int pack2(float lo, float hi) {
  return (unsigned int)f2bf(lo) | ((unsigned int)f2bf(hi) << 16);
}
__device__ __forceinline__ void gload_lds16(const unsigned short* g, unsigned short* l) {
  __builtin_amdgcn_global_load_lds(
      (const __attribute__((address_space(1))) void*)g,
      (__attribute__((address_space(3))) void*)l, 16, 0, 0);
}

#define BARX()  asm volatile("s_barrier" ::: "memory")
#define LGKM0() asm volatile("s_waitcnt lgkmcnt(0)" ::: "memory")
#define VM8()   asm volatile("s_waitcnt vmcnt(8)" ::: "memory")
#define VM6()   asm volatile("s_waitcnt vmcnt(6)" ::: "memory")
#define SB0()   __builtin_amdgcn_sched_barrier(0)

// ---------------- merged prep: fp32->bf16 conv + 2x weight transpose ----------------
__global__ void prep_kernel(const float* __restrict__ x, unsigned short* __restrict__ x_bf,
                            const float* __restrict__ w_qkv, unsigned short* __restrict__ wt_qkv,
                            const float* __restrict__ w_proj, unsigned short* __restrict__ wt_proj) {
  __shared__ float tile[32][33];
  int bid = blockIdx.x, t = threadIdx.x;
  if (bid < 2048) {
    long n = (long)M_TOT * DIM;
    long i = ((long)bid * 256 + t) * 8;
    long stride = (long)2048 * 256 * 8;
    for (; i < n; i += stride) {
      float4 a = *(const float4*)(x + i);
      float4 b = *(const float4*)(x + i + 4);
      uint4 o;
      o.x = pack2(a.x, a.y); o.y = pack2(a.z, a.w);
      o.z = pack2(b.x, b.y); o.w = pack2(b.z, b.w);
      *(uint4*)(x_bf + i) = o;
    }
  } else {
    const float* w; unsigned short* wt; int N, bx, by;
    if (bid < 2048 + 1728) {
      int r = bid - 2048; w = w_qkv; wt = wt_qkv; N = QKVC; bx = r % 72; by = r / 72;
    } else {
      int r = bid - 3776; w = w_proj; wt = wt_proj; N = DIM; bx = r % 24; by = r / 24;
    }
    int n0 = bx * 32, k0 = by * 32;
    int tx = t & 31, ty = t >> 5;
    #pragma unroll
    for (int i = 0; i < 32; i += 8)
      tile[ty + i][tx] = w[(size_t)(k0 + ty + i) * N + n0 + tx];
    __syncthreads();
    #pragma unroll
    for (int i = 0; i < 32; i += 8)
      wt[(size_t)(n0 + ty + i) * GK + k0 + tx] = f2bf(tile[tx][ty + i]);
  }
}

// ---------------- persistent 256x256x64 GEMM: R5 schedule, 32x32x16 MFMA ----------------
__device__ __forceinline__ void stage_half(const unsigned short* __restrict__ G, long row0, int col0,
                                           unsigned short* ldsHalf, int t) {
  int r = t >> 2;
  int gslot = (t & 3) ^ ((t >> 3) & 3);
  char* dst = (char*)ldsHalf + ((t >> 6) << 10);  // wave-uniform base; HW adds lane*16
  gload_lds16(G + (row0 + r) * (long)GK + col0 + gslot * 8, (unsigned short*)dst);
  gload_lds16(G + (row0 + 128 + r) * (long)GK + col0 + gslot * 8, (unsigned short*)(dst + 8192));
}
// r = absolute row in [0,256); ck = desired global chunk (kstep*2 + (lane>>5)); swizzled.
__device__ __forceinline__ bf16x8 frag32(const unsigned short* half, int r, int ck) {
  return *(const bf16x8*)((const char*)half + r * 64 + ((ck ^ ((r >> 1) & 3)) << 4));
}

// 8 MFMAs of 32x32x16: wave tile 128x64 = 4 rb x 2 cb. A held constant per pair.
#define MM8(A0,A1,A2,A3,B0,B1) do { \
  acc[0]=__builtin_amdgcn_mfma_f32_32x32x16_bf16(A0,B0,acc[0],0,0,0); \
  acc[1]=__builtin_amdgcn_mfma_f32_32x32x16_bf16(A0,B1,acc[1],0,0,0); \
  acc[2]=__builtin_amdgcn_mfma_f32_32x32x16_bf16(A1,B0,acc[2],0,0,0); \
  acc[3]=__builtin_amdgcn_mfma_f32_32x32x16_bf16(A1,B1,acc[3],0,0,0); \
  acc[4]=__builtin_amdgcn_mfma_f32_32x32x16_bf16(A2,B0,acc[4],0,0,0); \
  acc[5]=__builtin_amdgcn_mfma_f32_32x32x16_bf16(A2,B1,acc[5],0,0,0); \
  acc[6]=__builtin_amdgcn_mfma_f32_32x32x16_bf16(A3,B0,acc[6],0,0,0); \
  acc[7]=__builtin_amdgcn_mfma_f32_32x32x16_bf16(A3,B1,acc[7],0,0,0); \
} while (0)

// R5 K-tile ledger, 32x32 shape. Phases = ksteps: P1=ks0k0, P2=ks0k1, P3=ks1k0, P4=ks1k1.
// Per phase: LGKM0; MFMA(8); next-phase frag reads (6 x b128); stage; [VM6 at P1/P3]; BARX.
// VM6@P1(J) confirms S1,S2(J-1)=ks1(J) -> read end-P2/P3 (>=1 barrier after). VM6@P3(J)
// confirms S3,S4(J-1)=ks0(J+1) -> read end-P4. WAR: every region's last read drains
// (LGKM0) >=2 barriers before its overwriting stage. Verified incl. prologue + seams.
#define KTILE32(BUF, MA2, NB2, C2, MA3, NB3, C3) { \
  const unsigned short* Ah0 = &lds[BUF][0][0][0]; \
  const unsigned short* Bh0 = &lds[BUF][1][0][0]; \
  const unsigned short* Ah1 = &lds[BUF][0][1][0]; \
  const unsigned short* Bh1 = &lds[BUF][1][1][0]; \
  const unsigned short* Ah0n = &lds[(BUF) ^ 1][0][0][0]; \
  const unsigned short* Bh0n = &lds[(BUF) ^ 1][1][0][0]; \
  /* P1: MFMA ks0k0 (a0-3 x b0-1); reads ks0k1 -> a4-7,b2-3; stage S1; VM6 */ \
  LGKM0(); SB0(); \
  __builtin_amdgcn_s_setprio(1); MM8(a0, a1, a2, a3, b0, b1); \
  __builtin_amdgcn_s_setprio(0); SB0(); \
  a4 = frag32(Ah0, ra,      ck1); a5 = frag32(Ah0, ra + 32, ck1); \
  a6 = frag32(Ah0, ra + 64, ck1); a7 = frag32(Ah0, ra + 96, ck1); \
  b2 = frag32(Bh0, rbr,     ck1); b3 = frag32(Bh0, rbr + 32, ck1); \
  stage_half(A, MA2, C2, &lds[(BUF) ^ 1][0][1][0], t); \
  VM6(); BARX(); \
  /* P2: MFMA ks0k1 (a4-7 x b2-3); reads ks1k0 -> a0-3,b0-1; stage S2 */ \
  LGKM0(); SB0(); \
  __builtin_amdgcn_s_setprio(1); MM8(a4, a5, a6, a7, b2, b3); \
  __builtin_amdgcn_s_setprio(0); SB0(); \
  a0 = frag32(Ah1, ra,      ck0); a1 = frag32(Ah1, ra + 32, ck0); \
  a2 = frag32(Ah1, ra + 64, ck0); a3 = frag32(Ah1, ra + 96, ck0); \
  b0 = frag32(Bh1, rbr,     ck0); b1 = frag32(Bh1, rbr + 32, ck0); \
  stage_half(Bt, NB2, C2, &lds[(BUF) ^ 1][1][1][0], t); \
  BARX(); \
  /* P3: MFMA ks1k0 (a0-3 x b0-1); reads ks1k1 -> a4-7,b2-3; stage S3; VM6 */ \
  LGKM0(); SB0(); \
  __builtin_amdgcn_s_setprio(1); MM8(a0, a1, a2, a3, b0, b1); \
  __builtin_amdgcn_s_setprio(0); SB0(); \
  a4 = frag32(Ah1, ra,      ck1); a5 = frag32(Ah1, ra + 32, ck1); \
  a6 = frag32(Ah1, ra + 64, ck1); a7 = frag32(Ah1, ra + 96, ck1); \
  b2 = frag32(Bh1, rbr,     ck1); b3 = frag32(Bh1, rbr + 32, ck1); \
  stage_half(A, MA3, C3, &lds[BUF][0][0][0], t); \
  VM6(); BARX(); \
  /* P4: MFMA ks1k1 (a4-7 x b2-3); reads next ks0k0 -> a0-3,b0-1; stage S4 */ \
  LGKM0(); SB0(); \
  __builtin_amdgcn_s_setprio(1); MM8(a4, a5, a6, a7, b2, b3); \
  __builtin_amdgcn_s_setprio(0); SB0(); \
  a0 = frag32(Ah0n, ra,      ck0); a1 = frag32(Ah0n, ra + 32, ck0); \
  a2 = frag32(Ah0n, ra + 64, ck0); a3 = frag32(Ah0n, ra + 96, ck0); \
  b0 = frag32(Bh0n, rbr,     ck0); b1 = frag32(Bh0n, rbr + 32, ck0); \
  stage_half(Bt, NB3, C3, &lds[BUF][1][0][0], t); \
  BARX(); \
}

template<int OUTMODE, int NT>
__global__ __launch_bounds__(512, 2) void gemm256p(const unsigned short* __restrict__ A,
                                                   const unsigned short* __restrict__ Bt,
                                                   void* __restrict__ Cp,
                                                   const float* __restrict__ bias,
                                                   int Nld, int TPX) {
  __shared__ unsigned short lds[2][2][2][8192];  // [buf][A/B][ks][256*32], 128 KiB
  int t = threadIdx.x, lane = t & 63, wid = t >> 6;
  int wm = wid >> 2, wn = wid & 3;
  int bid = (int)blockIdx.x;
  int xcd = bid & 7, slot = bid >> 3;
  int tau = xcd * TPX + slot;
  int tend = (xcd + 1) * TPX;
  int l31 = lane & 31, lh = lane >> 5;
  int ck0 = lh, ck1 = 2 + lh;
  int ra = wm * 128 + l31, rbr = wn * 64 + l31;
  f32x16 acc[8];
  bf16x8 a0, a1, a2, a3, a4, a5, a6, a7, b0, b1, b2, b3;
  // prologue: stage buf0(ks0,ks1)+buf1(ks0); VM8 confirms buf0-ks0; prime ks0k0 frags
  {
    long m0 = (long)(tau / NT) * 256, n0 = (long)(tau % NT) * 256;
    stage_half(A,  m0, 0,  &lds[0][0][0][0], t);
    stage_half(Bt, n0, 0,  &lds[0][1][0][0], t);
    stage_half(A,  m0, 32, &lds[0][0][1][0], t);
    stage_half(Bt, n0, 32, &lds[0][1][1][0], t);
    stage_half(A,  m0, 64, &lds[1][0][0][0], t);
    stage_half(Bt, n0, 64, &lds[1][1][0][0], t);
    VM8(); BARX();
    a0 = frag32(&lds[0][0][0][0], ra,      ck0); a1 = frag32(&lds[0][0][0][0], ra + 32, ck0);
    a2 = frag32(&lds[0][0][0][0], ra + 64, ck0); a3 = frag32(&lds[0][0][0][0], ra + 96, ck0);
    b0 = frag32(&lds[0][1][0][0], rbr,     ck0); b1 = frag32(&lds[0][1][0][0], rbr + 32, ck0);
  }
  #pragma unroll 1
  for (; tau < tend; tau += 32) {
    long m0 = (long)(tau / NT) * 256, n0 = (long)(tau % NT) * 256;
    int tn = (tau + 32 < tend) ? tau + 32 : tau;
    long m0n = (long)(tn / NT) * 256, n0n = (long)(tn % NT) * 256;
    #pragma unroll
    for (int i = 0; i < 8; ++i)
      #pragma unroll
      for (int j2 = 0; j2 < 16; ++j2) acc[i][j2] = 0.f;
    #pragma unroll 1
    for (int j = 0; j < 10; j += 2) {
      KTILE32(0, m0, n0, j * 64 + 96,  m0, n0, j * 64 + 128);
      KTILE32(1, m0, n0, j * 64 + 160, m0, n0, j * 64 + 192);
    }
    KTILE32(0, m0,  n0,  736, m0n, n0n, 0);   // J=10: ks1(11) + next ks0(K0)
    KTILE32(1, m0n, n0n, 32,  m0n, n0n, 64);  // J=11: next ks1(K0) + buf1 ks0(K1)
    // epilogue: 32x32 C layout: col = lane&31, row = (reg&3) + 8*(reg>>2) + 4*(lane>>5)
    #pragma unroll
    for (int rb2 = 0; rb2 < 4; ++rb2) {
      #pragma unroll
      for (int cb = 0; cb < 2; ++cb) {
        f32x16 v = acc[rb2 * 2 + cb];
        int col = (int)n0 + wn * 64 + cb * 32 + l31;
        long rowb = m0 + wm * 128 + rb2 * 32 + lh * 4;
        if (OUTMODE == 0) {
          unsigned short* C = (unsigned short*)Cp;
          bool doexp = (n0 < 2 * DIM);
          #pragma unroll
          for (int reg = 0; reg < 16; ++reg) {
            long row = rowb + (reg & 3) + 8 * (reg >> 2);
            float x = v[reg];
            C[(size_t)row * Nld + col] = f2bf(doexp ? __expf(x) : x);
          }
        } else {
          float* C = (float*)Cp;
          float bb = bias[col];
          #pragma unroll
          for (int reg = 0; reg < 16; ++reg) {
            long row = rowb + (reg & 3) + 8 * (reg >> 2);
            C[(size_t)row * Nld + col] = v[reg] + bb;
          }
        }
      }
    }
  }
}

// ---------------- ctx partials: chunk ch of 7, rows [ch*448,(ch+1)*448) ----------------
__global__ void ctx_part(const unsigned short* __restrict__ qkv, float* __restrict__ part,
                         float* __restrict__ dpart) {
  int blk = blockIdx.x;              // 384*7
  int bh = blk / 7, ch = blk - bh * 7;
  int b = bh / NH, h = bh % NH;
  __shared__ unsigned short Et[64 * 40];
  __shared__ unsigned short Vt[64 * 40];
  __shared__ float denom[64];
  int t = threadIdx.x, lane = t & 63, w = t >> 6;
  if (t < 64) denom[t] = 0.0f;
  int nl = t >> 3, e0 = (t & 7) * 8;
  int ko = (lane >> 4) * 8, fl = lane & 15;
  size_t base = (size_t)b * SEQ * QKVC + (size_t)h * HD;
  float dp[8] = {};
  f32x4 acc[4] = {};
  int c0b = ch * 448;
  for (int c0 = c0b; c0 < c0b + 448; c0 += 32) {
    __syncthreads();
    size_t rb = base + (size_t)(c0 + nl) * QKVC;
    uint4 kvec = *(const uint4*)(qkv + rb + DIM + e0);
    uint4 vvec = *(const uint4*)(qkv + rb + 2 * DIM + e0);
    const unsigned short* kp = (const unsigned short*)&kvec;
    const unsigned short* vp = (const unsigned short*)&vvec;
    #pragma unroll
    for (int j = 0; j < 8; ++j) {
      dp[j] += bf2f(kp[j]);
      Et[(e0 + j) * 40 + nl] = kp[j];
      Vt[(e0 + j) * 40 + nl] = vp[j];
    }
    __syncthreads();
    bf16x8 af = *(const bf16x8*)(Et + (w * 16 + fl) * 40 + ko);
    #pragma unroll
    for (int nf = 0; nf < 4; ++nf) {
      bf16x8 bv = *(const bf16x8*)(Vt + (nf * 16 + fl) * 40 + ko);
      acc[nf] = __builtin_amdgcn_mfma_f32_16x16x32_bf16(af, bv, acc[nf], 0, 0, 0);
    }
  }
  #pragma unroll
  for (int j = 0; j < 8; ++j) atomicAdd(&denom[e0 + j], dp[j]);
  __syncthreads();
  int r0 = (lane >> 4) * 4;
  float* pp = part + (size_t)blk * 4096;
  #pragma unroll
  for (int nf = 0; nf < 4; ++nf)
    #pragma unroll
    for (int r = 0; r < 4; ++r) {
      int c = w * 16 + r0 + r;
      int d = nf * 16 + fl;
      pp[d * 64 + c] = acc[nf][r];
    }
  if (t < 64) dpart[blk * 64 + t] = denom[t];
}

// ---------------- ctx reduce over 7 chunks -> ctxT[bh][d*64+c] bf16 ----------------
__global__ void ctx_reduce(const float* __restrict__ part, const float* __restrict__ dpart,
                           unsigned short* __restrict__ ctxT) {
  int bh = blockIdx.x, t = threadIdx.x;
  const float* pp = part + (size_t)bh * 7 * 4096;
  const float* dd = dpart + (size_t)bh * 7 * 64;
  #pragma unroll
  for (int i = 0; i < 16; ++i) {
    int idx = i * 256 + t;
    float s = 0.f, ds = 0.f;
    #pragma unroll
    for (int c = 0; c < 7; ++c) {
      s += pp[c * 4096 + idx];
      ds += dd[c * 64 + (idx & 63)];
    }
    ctxT[(size_t)bh * 4096 + idx] = f2bf(s / ds);
  }
}

// ---------------- PV: out[n][d] = (sum_c eq[n][c] ctx[c][d]) / sum_c eq[n][c] ----------------
__global__ void pv_kernel(const unsigned short* __restrict__ qkv, const unsigned short* __restrict__ ctxT,
                          unsigned short* __restrict__ aout) {
  int bid = blockIdx.x;
  int bh = bid / 49, chunk = bid - bh * 49;
  int b = bh / NH, h = bh % NH;
  int n0 = chunk * 64;
  __shared__ unsigned short P[64 * 80];
  __shared__ unsigned short CT[64 * 80];
  __shared__ float srow[64];
  int t = threadIdx.x, lane = t & 63, w = t >> 6;
  int ko = (lane >> 4) * 8, fl = lane & 15;
  if (t < 64) srow[t] = 0.0f;
  {
    int d = t >> 2, cq = (t & 3) * 16;
    const uint4* src = (const uint4*)(ctxT + (size_t)bh * 4096 + d * 64 + cq);
    *(uint4*)(CT + d * 80 + cq) = src[0];
    *(uint4*)(CT + d * 80 + cq + 8) = src[1];
  }
  __syncthreads();
  {
    int nl = t >> 2, cq = (t & 3) * 16;
    size_t rb = (size_t)(b * SEQ + n0 + nl) * QKVC + h * HD + cq;
    uint4 q0 = *(const uint4*)(qkv + rb);
    uint4 q1 = *(const uint4*)(qkv + rb + 8);
    *(uint4*)(P + nl * 80 + cq) = q0;
    *(uint4*)(P + nl * 80 + cq + 8) = q1;
    const unsigned short* qp0 = (const unsigned short*)&q0;
    const unsigned short* qp1 = (const unsigned short*)&q1;
    float s = 0.0f;
    #pragma unroll
    for (int j = 0; j < 8; ++j) s += bf2f(qp0[j]) + bf2f(qp1[j]);
    atomicAdd(&srow[nl], s);
  }
  __syncthreads();
  f32x4 acc[4] = {};
  #pragma unroll
  for (int kk = 0; kk < 2; ++kk) {
    bf16x8 af = *(const bf16x8*)(P + (w * 16 + fl) * 80 + kk * 32 + ko);
    #pragma unroll
    for (int nf = 0; nf < 4; ++nf) {
      bf16x8 bv = *(const bf16x8*)(CT + (nf * 16 + fl) * 80 + kk * 32 + ko);
      acc[nf] = __builtin_amdgcn_mfma_f32_16x16x32_bf16(af, bv, acc[nf], 0, 0, 0);
    }
  }
  int r0 = (lane >> 4) * 4;
  #pragma unroll
  for (int nf = 0; nf < 4; ++nf)
    #pragma unroll
    for (int r = 0; r < 4; ++r) {
      int nlr = w * 16 + r0 + r;
      int d = nf * 16 + fl;
      float v = acc[nf][r] / srow[nlr];
      aout[(size_t)(b * SEQ + n0 + nlr) * DIM + h * HD + d] = f2bf(v);
    }
}

extern "C" void kernel_launch(void* const* d_in, const int* in_sizes, int n_in,
                              void* d_out, int out_size, void* d_ws, size_t ws_size,
                              hipStream_t stream) {
  const float* x      = (const float*)d_in[0];
  const float* w_qkv  = (const float*)d_in[1];
  const float* w_proj = (const float*)d_in[2];
  const float* b_proj = (const float*)d_in[3];
  char* ws = (char*)d_ws;
  unsigned short* x_bf    = (unsigned short*)(ws);
  unsigned short* wt_qkv  = (unsigned short*)(ws + 154140672);
  unsigned short* wt_proj = (unsigned short*)(ws + 157679616);
  unsigned short* qkv     = (unsigned short*)(ws + 158859264);
  unsigned short* ctxT    = (unsigned short*)(ws + 154140672);  // alias wt_qkv (dead after GEMM1)
  float* part  = (float*)(ws);                 // alias x_bf region (dead after GEMM1), 44.0 MB
  float* dpart = (float*)(ws + 44040192);      // 688 KB
  unsigned short* aout = (unsigned short*)(ws);  // alias x_bf/part (partials dead after reduce)

  prep_kernel<<<4352, 256, 0, stream>>>(x, x_bf, w_qkv, wt_qkv, w_proj, wt_proj);
  gemm256p<0, 9><<<256, 512, 0, stream>>>(x_bf, wt_qkv, qkv, nullptr, QKVC, 441);
  ctx_part<<<BATCH * NH * 7, 256, 0, stream>>>(qkv, part, dpart);
  ctx_reduce<<<BATCH * NH, 256, 0, stream>>>(part, dpart, ctxT);
  pv_kernel<<<BATCH * NH * (SEQ / 64), 256, 0, stream>>>(qkv, ctxT, aout);
  gemm256p<1, 3><<<256, 512, 0, stream>>>(aout, wt_proj, (float*)d_out, b_proj, DIM, 147);
}

// Round 11
// 802.976 us; speedup vs baseline: 1.1434x; 1.0408x over previous
//
#include <hip/hip_runtime.h>
#include <hip/hip_bf16.h>

typedef __attribute__((ext_vector_type(8))) short bf16x8;
typedef __attribute__((ext_vector_type(4))) float f32x4;

constexpr int BATCH = 32, SEQ = 3136, DIM = 768, NH = 12, HD = 64;
constexpr int M_TOT = BATCH * SEQ;   // 100352
constexpr int QKVC  = 3 * DIM;       // 2304
constexpr int GK    = 768;           // K for both GEMMs

__device__ __forceinline__ float bf2f(unsigned short u) {
  union { unsigned int i; float f; } x; x.i = ((unsigned int)u) << 16; return x.f;
}
__device__ __forceinline__ unsigned short f2bf(float f) {
  union { float f; unsigned int i; } x; x.f = f;
  unsigned int r = x.i + 0x7FFFu + ((x.i >> 16) & 1u);
  return (unsigned short)(r >> 16);
}
__device__ __forceinline__ unsigned int pack2(float lo, float hi) {
  return (unsigned int)f2bf(lo) | ((unsigned int)f2bf(hi) << 16);
}
__device__ __forceinline__ void gload_lds16(const unsigned short* g, unsigned short* l) {
  __builtin_amdgcn_global_load_lds(
      (const __attribute__((address_space(1))) void*)g,
      (__attribute__((address_space(3))) void*)l, 16, 0, 0);
}

#define BARX()  asm volatile("s_barrier" ::: "memory")
#define LGKM0() asm volatile("s_waitcnt lgkmcnt(0)" ::: "memory")
#define VM8()   asm volatile("s_waitcnt vmcnt(8)" ::: "memory")
#define VM6()   asm volatile("s_waitcnt vmcnt(6)" ::: "memory")
#define SB0()   __builtin_amdgcn_sched_barrier(0)

// ---------------- merged prep: fp32->bf16 conv + 2x weight transpose ----------------
__global__ void prep_kernel(const float* __restrict__ x, unsigned short* __restrict__ x_bf,
                            const float* __restrict__ w_qkv, unsigned short* __restrict__ wt_qkv,
                            const float* __restrict__ w_proj, unsigned short* __restrict__ wt_proj) {
  __shared__ float tile[32][33];
  int bid = blockIdx.x, t = threadIdx.x;
  if (bid < 2048) {
    long n = (long)M_TOT * DIM;
    long i = ((long)bid * 256 + t) * 8;
    long stride = (long)2048 * 256 * 8;
    for (; i < n; i += stride) {
      float4 a = *(const float4*)(x + i);
      float4 b = *(const float4*)(x + i + 4);
      uint4 o;
      o.x = pack2(a.x, a.y); o.y = pack2(a.z, a.w);
      o.z = pack2(b.x, b.y); o.w = pack2(b.z, b.w);
      *(uint4*)(x_bf + i) = o;
    }
  } else {
    const float* w; unsigned short* wt; int N, bx, by;
    if (bid < 2048 + 1728) {
      int r = bid - 2048; w = w_qkv; wt = wt_qkv; N = QKVC; bx = r % 72; by = r / 72;
    } else {
      int r = bid - 3776; w = w_proj; wt = wt_proj; N = DIM; bx = r % 24; by = r / 24;
    }
    int n0 = bx * 32, k0 = by * 32;
    int tx = t & 31, ty = t >> 5;
    #pragma unroll
    for (int i = 0; i < 32; i += 8)
      tile[ty + i][tx] = w[(size_t)(k0 + ty + i) * N + n0 + tx];
    __syncthreads();
    #pragma unroll
    for (int i = 0; i < 32; i += 8)
      wt[(size_t)(n0 + ty + i) * GK + k0 + tx] = f2bf(tile[tx][ty + i]);
  }
}

// ---------------- persistent 256x256x64 GEMM, exact R5 structure (best measured) ----------------
__device__ __forceinline__ void stage_half(const unsigned short* __restrict__ G, long row0, int col0,
                                           unsigned short* ldsHalf, int t) {
  int r = t >> 2;
  int gslot = (t & 3) ^ ((t >> 3) & 3);
  char* dst = (char*)ldsHalf + ((t >> 6) << 10);  // wave-uniform base; HW adds lane*16
  gload_lds16(G + (row0 + r) * (long)GK + col0 + gslot * 8, (unsigned short*)dst);
  gload_lds16(G + (row0 + 128 + r) * (long)GK + col0 + gslot * 8, (unsigned short*)(dst + 8192));
}
__device__ __forceinline__ bf16x8 frag(const unsigned short* half, int r, int ko) {
  return *(const bf16x8*)((const char*)half + r * 64 + ((((ko >> 3) ^ ((r >> 1) & 3))) << 4));
}

#define MM16G(Q,A0,A1,A2,A3,B0,B1,B2,B3) do { \
  acc[(Q)+0][0]=__builtin_amdgcn_mfma_f32_16x16x32_bf16(A0,B0,acc[(Q)+0][0],0,0,0); \
  acc[(Q)+0][1]=__builtin_amdgcn_mfma_f32_16x16x32_bf16(A0,B1,acc[(Q)+0][1],0,0,0); \
  acc[(Q)+0][2]=__builtin_amdgcn_mfma_f32_16x16x32_bf16(A0,B2,acc[(Q)+0][2],0,0,0); \
  acc[(Q)+0][3]=__builtin_amdgcn_mfma_f32_16x16x32_bf16(A0,B3,acc[(Q)+0][3],0,0,0); \
  acc[(Q)+1][0]=__builtin_amdgcn_mfma_f32_16x16x32_bf16(A1,B0,acc[(Q)+1][0],0,0,0); \
  acc[(Q)+1][1]=__builtin_amdgcn_mfma_f32_16x16x32_bf16(A1,B1,acc[(Q)+1][1],0,0,0); \
  acc[(Q)+1][2]=__builtin_amdgcn_mfma_f32_16x16x32_bf16(A1,B2,acc[(Q)+1][2],0,0,0); \
  acc[(Q)+1][3]=__builtin_amdgcn_mfma_f32_16x16x32_bf16(A1,B3,acc[(Q)+1][3],0,0,0); \
  acc[(Q)+2][0]=__builtin_amdgcn_mfma_f32_16x16x32_bf16(A2,B0,acc[(Q)+2][0],0,0,0); \
  acc[(Q)+2][1]=__builtin_amdgcn_mfma_f32_16x16x32_bf16(A2,B1,acc[(Q)+2][1],0,0,0); \
  acc[(Q)+2][2]=__builtin_amdgcn_mfma_f32_16x16x32_bf16(A2,B2,acc[(Q)+2][2],0,0,0); \
  acc[(Q)+2][3]=__builtin_amdgcn_mfma_f32_16x16x32_bf16(A2,B3,acc[(Q)+2][3],0,0,0); \
  acc[(Q)+3][0]=__builtin_amdgcn_mfma_f32_16x16x32_bf16(A3,B0,acc[(Q)+3][0],0,0,0); \
  acc[(Q)+3][1]=__builtin_amdgcn_mfma_f32_16x16x32_bf16(A3,B1,acc[(Q)+3][1],0,0,0); \
  acc[(Q)+3][2]=__builtin_amdgcn_mfma_f32_16x16x32_bf16(A3,B2,acc[(Q)+3][2],0,0,0); \
  acc[(Q)+3][3]=__builtin_amdgcn_mfma_f32_16x16x32_bf16(A3,B3,acc[(Q)+3][3],0,0,0); \
} while (0)

// R5 K-tile, reads-after-MFMA order (best measured: 355us GEMM1, MfmaUtil 46%).
// VM6 ledger: VM6@P1(J) confirms S1,S2(J-1)=ks1(J) -> read end-P2/P3 (>=1 barrier later).
// VM6@P3(J) confirms S3,S4(J-1)=ks0(J+1) -> read end-P4. Holds for prologue and tile
// seams. WAR: every region's last ds_read drains (LGKM0) >=2 barriers before overwrite.
#define KTILE_W(BUF, MA2, NB2, C2, MA3, NB3, C3) { \
  const unsigned short* Ah0 = &lds[BUF][0][0][0]; \
  const unsigned short* Bh1 = &lds[BUF][1][1][0]; \
  const unsigned short* Ah1 = &lds[BUF][0][1][0]; \
  const unsigned short* Ah0n = &lds[(BUF) ^ 1][0][0][0]; \
  const unsigned short* Bh0n = &lds[(BUF) ^ 1][1][0][0]; \
  /* P1: MFMA ks0/mq0 (a0-3 x b0-3); reads a4-7 <- ks0 mq1; stage S1; VM6 */ \
  LGKM0(); SB0(); \
  __builtin_amdgcn_s_setprio(1); MM16G(0, a0, a1, a2, a3, b0, b1, b2, b3); \
  __builtin_amdgcn_s_setprio(0); SB0(); \
  a4 = frag(Ah0, ra + 64, ko); a5 = frag(Ah0, ra + 80, ko); \
  a6 = frag(Ah0, ra + 96, ko); a7 = frag(Ah0, ra + 112, ko); \
  stage_half(A, MA2, C2, &lds[(BUF) ^ 1][0][1][0], t); \
  VM6(); BARX(); \
  /* P2: MFMA ks0/mq1 (a4-7 x b0-3); reads a0-3 <- ks1 mq0, b4-7 <- ks1; stage S2 */ \
  LGKM0(); SB0(); \
  __builtin_amdgcn_s_setprio(1); MM16G(4, a4, a5, a6, a7, b0, b1, b2, b3); \
  __builtin_amdgcn_s_setprio(0); SB0(); \
  a0 = frag(Ah1, ra,      ko); a1 = frag(Ah1, ra + 16, ko); \
  a2 = frag(Ah1, ra + 32, ko); a3 = frag(Ah1, ra + 48, ko); \
  b4 = frag(Bh1, rb,      ko); b5 = frag(Bh1, rb + 16, ko); \
  b6 = frag(Bh1, rb + 32, ko); b7 = frag(Bh1, rb + 48, ko); \
  stage_half(Bt, NB2, C2, &lds[(BUF) ^ 1][1][1][0], t); \
  BARX(); \
  /* P3: MFMA ks1/mq0 (a0-3 x b4-7); reads a4-7 <- ks1 mq1; stage S3; VM6 */ \
  LGKM0(); SB0(); \
  __builtin_amdgcn_s_setprio(1); MM16G(0, a0, a1, a2, a3, b4, b5, b6, b7); \
  __builtin_amdgcn_s_setprio(0); SB0(); \
  a4 = frag(Ah1, ra + 64, ko); a5 = frag(Ah1, ra + 80, ko); \
  a6 = frag(Ah1, ra + 96, ko); a7 = frag(Ah1, ra + 112, ko); \
  stage_half(A, MA3, C3, &lds[BUF][0][0][0], t); \
  VM6(); BARX(); \
  /* P4: MFMA ks1/mq1 (a4-7 x b4-7); reads a0-3,b0-3 <- next ks0; stage S4 */ \
  LGKM0(); SB0(); \
  __builtin_amdgcn_s_setprio(1); MM16G(4, a4, a5, a6, a7, b4, b5, b6, b7); \
  __builtin_amdgcn_s_setprio(0); SB0(); \
  a0 = frag(Ah0n, ra,      ko); a1 = frag(Ah0n, ra + 16, ko); \
  a2 = frag(Ah0n, ra + 32, ko); a3 = frag(Ah0n, ra + 48, ko); \
  b0 = frag(Bh0n, rb,      ko); b1 = frag(Bh0n, rb + 16, ko); \
  b2 = frag(Bh0n, rb + 32, ko); b3 = frag(Bh0n, rb + 48, ko); \
  stage_half(Bt, NB3, C3, &lds[BUF][1][0][0], t); \
  BARX(); \
}

template<int OUTMODE, int NT>
__global__ __launch_bounds__(512, 2) void gemm256p(const unsigned short* __restrict__ A,
                                                   const unsigned short* __restrict__ Bt,
                                                   void* __restrict__ Cp,
                                                   const float* __restrict__ bias,
                                                   int Nld, int TPX) {
  __shared__ unsigned short lds[2][2][2][8192];  // [buf][A/B][ks][256*32], 128 KiB
  int t = threadIdx.x, lane = t & 63, wid = t >> 6;
  int wm = wid >> 2, wn = wid & 3;
  int bid = (int)blockIdx.x;
  int xcd = bid & 7, slot = bid >> 3;
  int tau = xcd * TPX + slot;
  int tend = (xcd + 1) * TPX;
  int fl = lane & 15, ko = (lane >> 4) * 8;
  int ra = wm * 128 + fl, rb = wn * 64 + fl;
  f32x4 acc[8][4];
  bf16x8 a0, a1, a2, a3, a4, a5, a6, a7, b0, b1, b2, b3, b4, b5, b6, b7;
  // prologue: stage buf0(ks0,ks1)+buf1(ks0); VM8 confirms buf0-ks0; prime a0-3,b0-3
  {
    long m0 = (long)(tau / NT) * 256, n0 = (long)(tau % NT) * 256;
    stage_half(A,  m0, 0,  &lds[0][0][0][0], t);
    stage_half(Bt, n0, 0,  &lds[0][1][0][0], t);
    stage_half(A,  m0, 32, &lds[0][0][1][0], t);
    stage_half(Bt, n0, 32, &lds[0][1][1][0], t);
    stage_half(A,  m0, 64, &lds[1][0][0][0], t);
    stage_half(Bt, n0, 64, &lds[1][1][0][0], t);
    VM8(); BARX();
    a0 = frag(&lds[0][0][0][0], ra,      ko); a1 = frag(&lds[0][0][0][0], ra + 16, ko);
    a2 = frag(&lds[0][0][0][0], ra + 32, ko); a3 = frag(&lds[0][0][0][0], ra + 48, ko);
    b0 = frag(&lds[0][1][0][0], rb,      ko); b1 = frag(&lds[0][1][0][0], rb + 16, ko);
    b2 = frag(&lds[0][1][0][0], rb + 32, ko); b3 = frag(&lds[0][1][0][0], rb + 48, ko);
  }
  #pragma unroll 1
  for (; tau < tend; tau += 32) {
    long m0 = (long)(tau / NT) * 256, n0 = (long)(tau % NT) * 256;
    int tn = (tau + 32 < tend) ? tau + 32 : tau;
    long m0n = (long)(tn / NT) * 256, n0n = (long)(tn % NT) * 256;
    #pragma unroll
    for (int i = 0; i < 8; ++i)
      #pragma unroll
      for (int j2 = 0; j2 < 4; ++j2) acc[i][j2] = (f32x4){0.f, 0.f, 0.f, 0.f};
    #pragma unroll 1
    for (int j = 0; j < 10; j += 2) {
      KTILE_W(0, m0, n0, j * 64 + 96,  m0, n0, j * 64 + 128);
      KTILE_W(1, m0, n0, j * 64 + 160, m0, n0, j * 64 + 192);
    }
    KTILE_W(0, m0,  n0,  736, m0n, n0n, 0);   // J=10: ks1(11) + next ks0(K0)
    KTILE_W(1, m0n, n0n, 32,  m0n, n0n, 64);  // J=11: next ks1(K0) + buf1 ks0(K1)
    // epilogue (register-only source; overlaps in-flight next-tile stages)
    int r0 = (lane >> 4) * 4;
    #pragma unroll
    for (int mf = 0; mf < 8; ++mf) {
      #pragma unroll
      for (int nf = 0; nf < 4; ++nf) {
        long row = m0 + wm * 128 + mf * 16 + r0;
        int col = (int)n0 + wn * 64 + nf * 16 + fl;
        if (OUTMODE == 0) {
          unsigned short* C = (unsigned short*)Cp;
          bool doexp = (n0 < 2 * DIM);
          #pragma unroll
          for (int r = 0; r < 4; ++r) {
            float v = acc[mf][nf][r];
            C[(size_t)(row + r) * Nld + col] = f2bf(doexp ? __expf(v) : v);
          }
        } else {
          float* C = (float*)Cp;
          float bb = bias[col];
          #pragma unroll
          for (int r = 0; r < 4; ++r)
            C[(size_t)(row + r) * Nld + col] = acc[mf][nf][r] + bb;
        }
      }
    }
  }
}

// ---------------- ctx partials: chunk ch of 7, rows [ch*448,(ch+1)*448) ----------------
__global__ void ctx_part(const unsigned short* __restrict__ qkv, float* __restrict__ part,
                         float* __restrict__ dpart) {
  int blk = blockIdx.x;              // 384*7
  int bh = blk / 7, ch = blk - bh * 7;
  int b = bh / NH, h = bh % NH;
  __shared__ unsigned short Et[64 * 40];
  __shared__ unsigned short Vt[64 * 40];
  __shared__ float denom[64];
  int t = threadIdx.x, lane = t & 63, w = t >> 6;
  if (t < 64) denom[t] = 0.0f;
  int nl = t >> 3, e0 = (t & 7) * 8;
  int ko = (lane >> 4) * 8, fl = lane & 15;
  size_t base = (size_t)b * SEQ * QKVC + (size_t)h * HD;
  float dp[8] = {};
  f32x4 acc[4] = {};
  int c0b = ch * 448;
  for (int c0 = c0b; c0 < c0b + 448; c0 += 32) {
    __syncthreads();
    size_t rb = base + (size_t)(c0 + nl) * QKVC;
    uint4 kvec = *(const uint4*)(qkv + rb + DIM + e0);
    uint4 vvec = *(const uint4*)(qkv + rb + 2 * DIM + e0);
    const unsigned short* kp = (const unsigned short*)&kvec;
    const unsigned short* vp = (const unsigned short*)&vvec;
    #pragma unroll
    for (int j = 0; j < 8; ++j) {
      dp[j] += bf2f(kp[j]);
      Et[(e0 + j) * 40 + nl] = kp[j];
      Vt[(e0 + j) * 40 + nl] = vp[j];
    }
    __syncthreads();
    bf16x8 af = *(const bf16x8*)(Et + (w * 16 + fl) * 40 + ko);
    #pragma unroll
    for (int nf = 0; nf < 4; ++nf) {
      bf16x8 bv = *(const bf16x8*)(Vt + (nf * 16 + fl) * 40 + ko);
      acc[nf] = __builtin_amdgcn_mfma_f32_16x16x32_bf16(af, bv, acc[nf], 0, 0, 0);
    }
  }
  #pragma unroll
  for (int j = 0; j < 8; ++j) atomicAdd(&denom[e0 + j], dp[j]);
  __syncthreads();
  int r0 = (lane >> 4) * 4;
  float* pp = part + (size_t)blk * 4096;
  #pragma unroll
  for (int nf = 0; nf < 4; ++nf)
    #pragma unroll
    for (int r = 0; r < 4; ++r) {
      int c = w * 16 + r0 + r;
      int d = nf * 16 + fl;
      pp[d * 64 + c] = acc[nf][r];
    }
  if (t < 64) dpart[blk * 64 + t] = denom[t];
}

// ---------------- ctx reduce over 7 chunks -> ctxT[bh][d*64+c] bf16 ----------------
__global__ void ctx_reduce(const float* __restrict__ part, const float* __restrict__ dpart,
                           unsigned short* __restrict__ ctxT) {
  int bh = blockIdx.x, t = threadIdx.x;
  const float* pp = part + (size_t)bh * 7 * 4096;
  const float* dd = dpart + (size_t)bh * 7 * 64;
  #pragma unroll
  for (int i = 0; i < 16; ++i) {
    int idx = i * 256 + t;
    float s = 0.f, ds = 0.f;
    #pragma unroll
    for (int c = 0; c < 7; ++c) {
      s += pp[c * 4096 + idx];
      ds += dd[c * 64 + (idx & 63)];
    }
    ctxT[(size_t)bh * 4096 + idx] = f2bf(s / ds);
  }
}

// ---------------- PV: out[n][d] = (sum_c eq[n][c] ctx[c][d]) / sum_c eq[n][c] ----------------
__global__ void pv_kernel(const unsigned short* __restrict__ qkv, const unsigned short* __restrict__ ctxT,
                          unsigned short* __restrict__ aout) {
  int bid = blockIdx.x;
  int bh = bid / 49, chunk = bid - bh * 49;
  int b = bh / NH, h = bh % NH;
  int n0 = chunk * 64;
  __shared__ unsigned short P[64 * 80];
  __shared__ unsigned short CT[64 * 80];
  __shared__ float srow[64];
  int t = threadIdx.x, lane = t & 63, w = t >> 6;
  int ko = (lane >> 4) * 8, fl = lane & 15;
  if (t < 64) srow[t] = 0.0f;
  {
    int d = t >> 2, cq = (t & 3) * 16;
    const uint4* src = (const uint4*)(ctxT + (size_t)bh * 4096 + d * 64 + cq);
    *(uint4*)(CT + d * 80 + cq) = src[0];
    *(uint4*)(CT + d * 80 + cq + 8) = src[1];
  }
  __syncthreads();
  {
    int nl = t >> 2, cq = (t & 3) * 16;
    size_t rb = (size_t)(b * SEQ + n0 + nl) * QKVC + h * HD + cq;
    uint4 q0 = *(const uint4*)(qkv + rb);
    uint4 q1 = *(const uint4*)(qkv + rb + 8);
    *(uint4*)(P + nl * 80 + cq) = q0;
    *(uint4*)(P + nl * 80 + cq + 8) = q1;
    const unsigned short* qp0 = (const unsigned short*)&q0;
    const unsigned short* qp1 = (const unsigned short*)&q1;
    float s = 0.0f;
    #pragma unroll
    for (int j = 0; j < 8; ++j) s += bf2f(qp0[j]) + bf2f(qp1[j]);
    atomicAdd(&srow[nl], s);
  }
  __syncthreads();
  f32x4 acc[4] = {};
  #pragma unroll
  for (int kk = 0; kk < 2; ++kk) {
    bf16x8 af = *(const bf16x8*)(P + (w * 16 + fl) * 80 + kk * 32 + ko);
    #pragma unroll
    for (int nf = 0; nf < 4; ++nf) {
      bf16x8 bv = *(const bf16x8*)(CT + (nf * 16 + fl) * 80 + kk * 32 + ko);
      acc[nf] = __builtin_amdgcn_mfma_f32_16x16x32_bf16(af, bv, acc[nf], 0, 0, 0);
    }
  }
  int r0 = (lane >> 4) * 4;
  #pragma unroll
  for (int nf = 0; nf < 4; ++nf)
    #pragma unroll
    for (int r = 0; r < 4; ++r) {
      int nlr = w * 16 + r0 + r;
      int d = nf * 16 + fl;
      float v = acc[nf][r] / srow[nlr];
      aout[(size_t)(b * SEQ + n0 + nlr) * DIM + h * HD + d] = f2bf(v);
    }
}

extern "C" void kernel_launch(void* const* d_in, const int* in_sizes, int n_in,
                              void* d_out, int out_size, void* d_ws, size_t ws_size,
                              hipStream_t stream) {
  const float* x      = (const float*)d_in[0];
  const float* w_qkv  = (const float*)d_in[1];
  const float* w_proj = (const float*)d_in[2];
  const float* b_proj = (const float*)d_in[3];
  char* ws = (char*)d_ws;
  unsigned short* x_bf    = (unsigned short*)(ws);
  unsigned short* wt_qkv  = (unsigned short*)(ws + 154140672);
  unsigned short* wt_proj = (unsigned short*)(ws + 157679616);
  unsigned short* qkv     = (unsigned short*)(ws + 158859264);
  unsigned short* ctxT    = (unsigned short*)(ws + 154140672);  // alias wt_qkv (dead after GEMM1)
  float* part  = (float*)(ws);                 // alias x_bf region (dead after GEMM1), 44.0 MB
  float* dpart = (float*)(ws + 44040192);      // 688 KB
  unsigned short* aout = (unsigned short*)(ws);  // alias x_bf/part (partials dead after reduce)

  prep_kernel<<<4352, 256, 0, stream>>>(x, x_bf, w_qkv, wt_qkv, w_proj, wt_proj);
  gemm256p<0, 9><<<256, 512, 0, stream>>>(x_bf, wt_qkv, qkv, nullptr, QKVC, 441);
  ctx_part<<<BATCH * NH * 7, 256, 0, stream>>>(qkv, part, dpart);
  ctx_reduce<<<BATCH * NH, 256, 0, stream>>>(part, dpart, ctxT);
  pv_kernel<<<BATCH * NH * (SEQ / 64), 256, 0, stream>>>(qkv, ctxT, aout);
  gemm256p<1, 3><<<256, 512, 0, stream>>>(aout, wt_proj, (float*)d_out, b_proj, DIM, 147);
}